// Round 10
// baseline (832.986 us; speedup 1.0000x reference)
//
#include <hip/hip_runtime.h>

// Conv1dFFTInt8: B=16, CIN=128, COUT=128, L=4096, out_size==1.
// Identity: ifft(sum_l X[l]W[l])[0] = sum_n x[n] * w[(L-n) mod L]  (real inputs)
// => out[b,o] = bias[o] + sum_i sum_m w[o,i,m] * x[b,i,(L-m)&(L-1)]
//
// Ledger: dur_us = conv + ~267us harness const. R4-R9: every schedule variant
// of the (o-tile x ci) decomposition = 105-115us vs 48us floor. Root cause
// candidates (untestable separately without clean counters): 8x x re-staging
// whose L2-hit status was never verified (worst case 512 MB fabric traffic =
// the observed time), and barrier-lockstep HBM burst/starve.
// This round changes the DECOMPOSITION: block = (ci, 512-float m-slice),
// computes partials for ALL 128 COUT. Weights AND x each read exactly once
// machine-wide (288 MB HBM total, no L2-reuse assumptions). x staged to LDS
// once; ZERO main-loop barriers (waves drift -> smooth HBM demand). Per
// o-pass: 512 FMAs, weight reload (hidden under flush), wave-private LDS
// transpose flush (stride 66: conflict-free, no cross-wave sync) -> 4-lane
// global atomicAdds (524K total). acc 64 + wc 32 ~= 116 VGPR (R8's proven
// budget). LDS 49.7 KB -> 3 blocks/CU; BW-bound so occupancy 12 waves/CU
// with 8KB in flight each >> 9.2KB latency-hiding requirement.

constexpr int LEN   = 4096;
constexpr int CIN_  = 128;
constexpr int COUT_ = 128;
constexpr int BATCH = 16;

typedef float f32x4 __attribute__((ext_vector_type(4)));

__global__ void init_out_kernel(const float* __restrict__ bias, float* __restrict__ out) {
    int t = blockIdx.x * 256 + threadIdx.x;
    if (t < BATCH * COUT_) out[t] = bias[t & (COUT_ - 1)];
}

// Non-temporal 16B weight load: read-once stream.
__device__ __forceinline__ f32x4 ntload4(const float* p) {
    return __builtin_nontemporal_load((const f32x4*)p);
}

// Async 4B global->LDS. LDS dest is wave-uniform base (+lane*4 in HW);
// the index reversal lives in the per-lane GLOBAL address.
__device__ __forceinline__ void gload_lds4(const float* g, float* l) {
    __builtin_amdgcn_global_load_lds(
        (const __attribute__((address_space(1))) unsigned int*)g,
        (__attribute__((address_space(3))) unsigned int*)l, 4, 0, 0);
}

// Block: 256 threads = 4 waves. Owns (ci, msplit): all 128 o for one
// 512-float m-slice. Grid = 8 msplit * 128 ci = 1024 blocks.
__global__ __launch_bounds__(256, 2)
void conv_fft_dot_kernel(const float* __restrict__ x, const float* __restrict__ w,
                         float* __restrict__ out) {
    // 49,664 B: x slice (16b x 512 = 32 KB) + 4 wave-private 16x66 flush regions.
    __shared__ float xls[8192];
    __shared__ float fl[4 * 16 * 66];

    const int tid  = threadIdx.x;
    const int lane = tid & 63;
    const int wv   = __builtin_amdgcn_readfirstlane(tid >> 6);
    const int bk   = blockIdx.x;
    const int ms   = bk >> 7;          // m-split 0..7
    const int ci   = bk & 127;         // input channel
    const int m0   = ms << 9;

    // ---- one-time stage: xls[b*512 + u] = x[b, ci, (LEN - m0 - u) & 4095]
#pragma unroll
    for (int bb = 0; bb < 4; ++bb) {
        const int b = 4 * wv + bb;
        const float* xc = x + ((b * CIN_ + ci) << 12);
        float* dst = xls + (b << 9);
#pragma unroll
        for (int t = 0; t < 8; ++t) {
            const int n = (LEN - m0 - (t << 6) - lane) & (LEN - 1);  // reversed src
            gload_lds4(xc + n, dst + (t << 6));
        }
    }
    // unit-0 weights issued behind the stage (drained together below, once)
    f32x4 wc[8];
#pragma unroll
    for (int j = 0; j < 4; ++j) {
        const float* wr = w + ((((wv * 4 + j) << 7) + ci) << 12) + m0;
        wc[j]     = ntload4(wr + (lane << 2));
        wc[4 + j] = ntload4(wr + 256 + (lane << 2));
    }
    __syncthreads();   // the ONLY block-wide barrier in this kernel

    float acc[16][4];
#pragma unroll
    for (int b = 0; b < 16; ++b)
#pragma unroll
        for (int j = 0; j < 4; ++j) acc[b][j] = 0.f;

    const float4* xls4 = (const float4*)xls;
    float* fr = fl + wv * (16 * 66);   // this wave's private flush region

#pragma unroll 1
    for (int u = 0; u < 8; ++u) {
        // ---- 512 FMAs: this unit's 16 o-rows (wave rows u*16 + wv*4 + j)
#pragma unroll
        for (int b = 0; b < 16; ++b) {
            const float4 xv0 = xls4[(b << 7) + lane];
            const float4 xv1 = xls4[(b << 7) + 64 + lane];
#pragma unroll
            for (int j = 0; j < 4; ++j) {
                acc[b][j] += xv0.x * wc[j].x + xv0.y * wc[j].y
                           + xv0.z * wc[j].z + xv0.w * wc[j].w;
                acc[b][j] += xv1.x * wc[4 + j].x + xv1.y * wc[4 + j].y
                           + xv1.z * wc[4 + j].z + xv1.w * wc[4 + j].w;
            }
        }
        // ---- issue next unit's weights NOW; the flush below hides the latency
        if (u < 7) {
            const int row = (u + 1) * 16 + wv * 4;
#pragma unroll
            for (int j = 0; j < 4; ++j) {
                const float* wr = w + ((((row + j) << 7) + ci) << 12) + m0;
                wc[j]     = ntload4(wr + (lane << 2));
                wc[4 + j] = ntload4(wr + 256 + (lane << 2));
            }
        }
        __builtin_amdgcn_sched_barrier(0);  // loads issued before flush ops
        // ---- wave-private flush: transpose-reduce acc -> global atomics.
        // Stride 66: writes (2r+lane)%32 2-way free; float2 reads 8B-aligned,
        // (2r+16c+2k)%32 2-way free. No cross-wave sync needed (region private).
        // All indices static (rule #20); u enters addresses only.
#pragma unroll
        for (int p = 0; p < 4; ++p) {
#pragma unroll
            for (int bb = 0; bb < 4; ++bb)
#pragma unroll
                for (int j = 0; j < 4; ++j)
                    fr[(bb * 4 + j) * 66 + lane] = acc[p * 4 + bb][j];
            const int r = lane & 15, c = lane >> 4;
            const float* rowp = fr + r * 66 + c * 16;
            float s = 0.f;
#pragma unroll
            for (int k = 0; k < 8; ++k) s += rowp[2 * k] + rowp[2 * k + 1];
            const int b = p * 4 + (r >> 2);
            const int o = u * 16 + wv * 4 + (r & 3);
            atomicAdd(out + b * COUT_ + o, s);   // 4 lanes/address, 16 addrs/instr
#pragma unroll
            for (int bb = 0; bb < 4; ++bb)
#pragma unroll
                for (int j = 0; j < 4; ++j)
                    acc[p * 4 + bb][j] = 0.f;
        }
    }
}

extern "C" void kernel_launch(void* const* d_in, const int* in_sizes, int n_in,
                              void* d_out, int out_size, void* d_ws, size_t ws_size,
                              hipStream_t stream) {
    const float* x    = (const float*)d_in[0];   // [16,128,4096]
    const float* wgt  = (const float*)d_in[1];   // [128,128,4096]
    const float* bias = (const float*)d_in[2];   // [128]
    float* out = (float*)d_out;                  // [16,128,1]
    (void)in_sizes; (void)n_in; (void)d_ws; (void)ws_size; (void)out_size;

    init_out_kernel<<<8, 256, 0, stream>>>(bias, out);
    conv_fft_dot_kernel<<<1024, 256, 0, stream>>>(x, wgt, out);
}

// Round 11
// 384.023 us; speedup vs baseline: 2.1691x; 2.1691x over previous
//
#include <hip/hip_runtime.h>

// Conv1dFFTInt8: B=16, CIN=128, COUT=128, L=4096, out_size==1.
// Identity: ifft(sum_l X[l]W[l])[0] = sum_n x[n] * w[(L-n) mod L]  (real inputs)
// => out[b,o] = bias[o] + sum_i sum_m w[o,i,m] * x[b,i,(L-m)&(L-1)]
//
// R10 post-mortem: read-once decomposition VERIFIED on the read side
// (FETCH 147MB, no spill, no conflicts) but 8.4M device atomics onto 2048
// addresses = 4096-deep serialization chains (152ns each) -> 625us, 349GB/s.
// This round: identical read structure, write path replaced by split-K
// partials in d_ws (8MB, private per block, non-atomic) + a reduce kernel
// (coalesced, atomic fan-in 8). Cross-lane c-sum via 2 shfl_xor instead of
// 4-way atomic contention.
//
// Traffic: weights 256MB + x 32MB read once machine-wide + 8MB ws write +
// 8MB ws read => ~304MB @ ~6TB/s ~= 50us + ~5us reduce.

constexpr int LEN   = 4096;
constexpr int CIN_  = 128;
constexpr int COUT_ = 128;
constexpr int BATCH = 16;

typedef float f32x4 __attribute__((ext_vector_type(4)));

__global__ void init_out_kernel(const float* __restrict__ bias, float* __restrict__ out) {
    int t = blockIdx.x * 256 + threadIdx.x;
    if (t < BATCH * COUT_) out[t] = bias[t & (COUT_ - 1)];
}

// Non-temporal 16B weight load: read-once stream.
__device__ __forceinline__ f32x4 ntload4(const float* p) {
    return __builtin_nontemporal_load((const f32x4*)p);
}

// Async 4B global->LDS. LDS dest is wave-uniform base (+lane*4 in HW);
// the index reversal lives in the per-lane GLOBAL address.
__device__ __forceinline__ void gload_lds4(const float* g, float* l) {
    __builtin_amdgcn_global_load_lds(
        (const __attribute__((address_space(1))) unsigned int*)g,
        (__attribute__((address_space(3))) unsigned int*)l, 4, 0, 0);
}

// Block: 256 threads = 4 waves. Owns (ci, msplit): all 128 o for one
// 512-float m-slice. Grid = 8 msplit * 128 ci = 1024 blocks. Partials go to
// ws[bk][b*128+o] (8MB), summed by reduce_ws_kernel.
__global__ __launch_bounds__(256, 2)
void conv_partial_kernel(const float* __restrict__ x, const float* __restrict__ w,
                         float* __restrict__ ws) {
    // 48.9 KB: x slice (16b x 512 = 32 KB) + 4 wave-private 16x66 flush regions.
    __shared__ float xls[8192];
    __shared__ float fl[4 * 16 * 66];

    const int tid  = threadIdx.x;
    const int lane = tid & 63;
    const int wv   = __builtin_amdgcn_readfirstlane(tid >> 6);
    const int bk   = blockIdx.x;
    const int ms   = bk >> 7;          // m-split 0..7
    const int ci   = bk & 127;         // input channel
    const int m0   = ms << 9;

    // ---- one-time stage: xls[b*512 + u] = x[b, ci, (LEN - m0 - u) & 4095]
#pragma unroll
    for (int bb = 0; bb < 4; ++bb) {
        const int b = 4 * wv + bb;
        const float* xc = x + ((b * CIN_ + ci) << 12);
        float* dst = xls + (b << 9);
#pragma unroll
        for (int t = 0; t < 8; ++t) {
            const int n = (LEN - m0 - (t << 6) - lane) & (LEN - 1);  // reversed src
            gload_lds4(xc + n, dst + (t << 6));
        }
    }
    // unit-0 weights issued behind the stage (drained together below, once)
    f32x4 wc[8];
#pragma unroll
    for (int j = 0; j < 4; ++j) {
        const float* wr = w + ((((wv * 4 + j) << 7) + ci) << 12) + m0;
        wc[j]     = ntload4(wr + (lane << 2));
        wc[4 + j] = ntload4(wr + 256 + (lane << 2));
    }
    __syncthreads();   // the ONLY block-wide barrier in this kernel

    float acc[16][4];
#pragma unroll
    for (int b = 0; b < 16; ++b)
#pragma unroll
        for (int j = 0; j < 4; ++j) acc[b][j] = 0.f;

    const float4* xls4 = (const float4*)xls;
    float* fr  = fl + wv * (16 * 66);       // this wave's private flush region
    float* wsb = ws + (size_t)bk * 2048;    // this block's private partial slab

#pragma unroll 1
    for (int u = 0; u < 8; ++u) {
        // ---- 512 FMAs: this unit's 16 o-rows (o = u*16 + wv*4 + j)
#pragma unroll
        for (int b = 0; b < 16; ++b) {
            const float4 xv0 = xls4[(b << 7) + lane];
            const float4 xv1 = xls4[(b << 7) + 64 + lane];
#pragma unroll
            for (int j = 0; j < 4; ++j) {
                acc[b][j] += xv0.x * wc[j].x + xv0.y * wc[j].y
                           + xv0.z * wc[j].z + xv0.w * wc[j].w;
                acc[b][j] += xv1.x * wc[4 + j].x + xv1.y * wc[4 + j].y
                           + xv1.z * wc[4 + j].z + xv1.w * wc[4 + j].w;
            }
        }
        // ---- issue next unit's weights NOW; the flush below hides the latency
        if (u < 7) {
            const int row = (u + 1) * 16 + wv * 4;
#pragma unroll
            for (int j = 0; j < 4; ++j) {
                const float* wr = w + ((((row + j) << 7) + ci) << 12) + m0;
                wc[j]     = ntload4(wr + (lane << 2));
                wc[4 + j] = ntload4(wr + 256 + (lane << 2));
            }
        }
        __builtin_amdgcn_sched_barrier(0);  // loads issued before flush ops
        // ---- wave-private flush: LDS transpose (stride 66, conflict-clean,
        // DS ops in-order per wave, no sync needed) -> 2 shfl_xor c-sum ->
        // ONE non-atomic ws store per (b,o). All indices static (rule #20).
#pragma unroll
        for (int p = 0; p < 4; ++p) {
#pragma unroll
            for (int bb = 0; bb < 4; ++bb)
#pragma unroll
                for (int j = 0; j < 4; ++j)
                    fr[(bb * 4 + j) * 66 + lane] = acc[p * 4 + bb][j];
            const int r = lane & 15, c = lane >> 4;
            const float* rowp = fr + r * 66 + c * 16;
            float s = 0.f;
#pragma unroll
            for (int k = 0; k < 8; ++k) s += rowp[2 * k] + rowp[2 * k + 1];
            s += __shfl_xor(s, 16);   // sum the 4 c-quarters
            s += __shfl_xor(s, 32);
            if (lane < 16) {
                const int b = p * 4 + (lane >> 2);
                const int o = u * 16 + wv * 4 + (lane & 3);
                wsb[b * COUT_ + o] = s;     // private slab: no atomic, no race
            }
#pragma unroll
            for (int bb = 0; bb < 4; ++bb)
#pragma unroll
                for (int j = 0; j < 4; ++j)
                    acc[p * 4 + bb][j] = 0.f;
        }
    }
}

// Reduce: out[bo] += sum_s ws[s][bo].  Grid 64 = 8 bo-chunks x 8 s-chunks;
// threads adjacent in bo -> every load coalesced (256B/wave/step).
// Atomic fan-in per out element: 8 (trivial).
__global__ __launch_bounds__(256, 4)
void reduce_ws_kernel(const float* __restrict__ ws, float* __restrict__ out) {
    const int bo = ((blockIdx.x & 7) << 8) + threadIdx.x;
    const int s0 = (blockIdx.x >> 3) << 7;
    const float* p = ws + (size_t)s0 * 2048 + bo;
    float s = 0.f;
#pragma unroll 8
    for (int i = 0; i < 128; ++i) s += p[(size_t)i * 2048];
    atomicAdd(out + bo, s);
}

extern "C" void kernel_launch(void* const* d_in, const int* in_sizes, int n_in,
                              void* d_out, int out_size, void* d_ws, size_t ws_size,
                              hipStream_t stream) {
    const float* x    = (const float*)d_in[0];   // [16,128,4096]
    const float* wgt  = (const float*)d_in[1];   // [128,128,4096]
    const float* bias = (const float*)d_in[2];   // [128]
    float* out = (float*)d_out;                  // [16,128,1]
    float* ws  = (float*)d_ws;                   // >= 8 MB (poisoned w/ 1GiB fills)
    (void)in_sizes; (void)n_in; (void)ws_size; (void)out_size;

    init_out_kernel<<<8, 256, 0, stream>>>(bias, out);
    conv_partial_kernel<<<1024, 256, 0, stream>>>(x, wgt, ws);
    reduce_ws_kernel<<<64, 256, 0, stream>>>(ws, out);
}

// Round 12
// 383.856 us; speedup vs baseline: 2.1700x; 1.0004x over previous
//
#include <hip/hip_runtime.h>

// Conv1dFFTInt8: B=16, CIN=128, COUT=128, L=4096, out_size==1.
// Identity: ifft(sum_l X[l]W[l])[0] = sum_n x[n] * w[(L-n) mod L]  (real inputs)
// => out[b,o] = bias[o] + sum_i sum_m w[o,i,m] * x[b,i,(L-m)&(L-1)]
//
// R11 post-mortem: atomics fixed, but the per-u flush = 128 b32 DS ops/wave/u
// -> ~75us of serialized LDS-unit time per CU > 47us memory floor. The LDS
// unit (one per CU) was the hidden bottleneck of the read-once decomposition.
// This round: DPP quad-reduce (VALU pipe, v_add_f32_dpp quad_perm) collapses
// each output's 64 lane-partials to 16 quad-sums BEFORE LDS; flush becomes
// 16 write + 16 read b32 per u (q^b XOR swizzle -> 2-way banks = free).
// LDS-unit time ~30us/CU < memory ~45us. fl shrinks 4x -> 48KB total LDS,
// 3 blocks/CU. Everything else (stage, wc prefetch, ws layout, reduce) = R11.

constexpr int LEN   = 4096;
constexpr int CIN_  = 128;
constexpr int COUT_ = 128;
constexpr int BATCH = 16;

typedef float f32x4 __attribute__((ext_vector_type(4)));

__global__ void init_out_kernel(const float* __restrict__ bias, float* __restrict__ out) {
    int t = blockIdx.x * 256 + threadIdx.x;
    if (t < BATCH * COUT_) out[t] = bias[t & (COUT_ - 1)];
}

// Non-temporal 16B weight load: read-once stream.
__device__ __forceinline__ f32x4 ntload4(const float* p) {
    return __builtin_nontemporal_load((const f32x4*)p);
}

// Async 4B global->LDS. LDS dest is wave-uniform base (+lane*4 in HW);
// the index reversal lives in the per-lane GLOBAL address.
__device__ __forceinline__ void gload_lds4(const float* g, float* l) {
    __builtin_amdgcn_global_load_lds(
        (const __attribute__((address_space(1))) unsigned int*)g,
        (__attribute__((address_space(3))) unsigned int*)l, 4, 0, 0);
}

// Quad (4-lane) sum on the VALU pipe via DPP quad_perm — zero LDS-unit cost.
// 0xB1 = quad_perm(1,0,3,2) (xor1), 0x4E = quad_perm(2,3,0,1) (xor2).
__device__ __forceinline__ float quad_sum(float v) {
    v += __int_as_float(__builtin_amdgcn_update_dpp(
            0, __float_as_int(v), 0xB1, 0xF, 0xF, true));
    v += __int_as_float(__builtin_amdgcn_update_dpp(
            0, __float_as_int(v), 0x4E, 0xF, 0xF, true));
    return v;   // all 4 lanes of the quad hold the quad total
}

// Block: 256 threads = 4 waves. Owns (ci, msplit): all 128 o for one
// 512-float m-slice. Grid = 8 msplit * 128 ci = 1024 blocks. Partials go to
// ws[bk][b*128+o] (8MB), summed by reduce_ws_kernel.
__global__ __launch_bounds__(256, 2)
void conv_partial_kernel(const float* __restrict__ x, const float* __restrict__ w,
                         float* __restrict__ ws) {
    // 48 KB: x slice (16b x 512 = 32 KB) + 4 wave-private 1024-float flush pads.
    __shared__ float xls[8192];
    __shared__ float fl[4096];

    const int tid  = threadIdx.x;
    const int lane = tid & 63;
    const int wv   = __builtin_amdgcn_readfirstlane(tid >> 6);
    const int bk   = blockIdx.x;
    const int ms   = bk >> 7;          // m-split 0..7
    const int ci   = bk & 127;         // input channel
    const int m0   = ms << 9;

    // ---- one-time stage: xls[b*512 + u] = x[b, ci, (LEN - m0 - u) & 4095]
#pragma unroll
    for (int bb = 0; bb < 4; ++bb) {
        const int b = 4 * wv + bb;
        const float* xc = x + ((b * CIN_ + ci) << 12);
        float* dst = xls + (b << 9);
#pragma unroll
        for (int t = 0; t < 8; ++t) {
            const int n = (LEN - m0 - (t << 6) - lane) & (LEN - 1);  // reversed src
            gload_lds4(xc + n, dst + (t << 6));
        }
    }
    // unit-0 weights issued behind the stage (drained together below, once)
    f32x4 wc[8];
#pragma unroll
    for (int j = 0; j < 4; ++j) {
        const float* wr = w + ((((wv * 4 + j) << 7) + ci) << 12) + m0;
        wc[j]     = ntload4(wr + (lane << 2));
        wc[4 + j] = ntload4(wr + 256 + (lane << 2));
    }
    __syncthreads();   // the ONLY block-wide barrier in this kernel

    float acc[16][4];
#pragma unroll
    for (int b = 0; b < 16; ++b)
#pragma unroll
        for (int j = 0; j < 4; ++j) acc[b][j] = 0.f;

    const float4* xls4 = (const float4*)xls;
    float* fr  = fl + (wv << 10);           // wave-private 1024-float pad
    float* wsb = ws + (size_t)bk * 2048;    // block-private partial slab
    const int q  = lane >> 2;               // quad id 0..15
    const int jo = lane & 3;                // o-sublane 0..3

#pragma unroll 1
    for (int u = 0; u < 8; ++u) {
        // ---- 512 FMAs: this unit's 16 o-rows (o = u*16 + wv*4 + j)
#pragma unroll
        for (int b = 0; b < 16; ++b) {
            const float4 xv0 = xls4[(b << 7) + lane];
            const float4 xv1 = xls4[(b << 7) + 64 + lane];
#pragma unroll
            for (int j = 0; j < 4; ++j) {
                acc[b][j] += xv0.x * wc[j].x + xv0.y * wc[j].y
                           + xv0.z * wc[j].z + xv0.w * wc[j].w;
                acc[b][j] += xv1.x * wc[4 + j].x + xv1.y * wc[4 + j].y
                           + xv1.z * wc[4 + j].z + xv1.w * wc[4 + j].w;
            }
        }
        // ---- issue next unit's weights NOW; the flush below hides the latency
        if (u < 7) {
            const int row = (u + 1) * 16 + wv * 4;
#pragma unroll
            for (int j = 0; j < 4; ++j) {
                const float* wr = w + ((((row + j) << 7) + ci) << 12) + m0;
                wc[j]     = ntload4(wr + (lane << 2));
                wc[4 + j] = ntload4(wr + 256 + (lane << 2));
            }
        }
        __builtin_amdgcn_sched_barrier(0);  // loads issued before flush ops
        // ---- flush: DPP quad-reduce (VALU) -> 16 b32 writes + 16 b32 reads.
        // Write: quad q's 4 lanes each store one component jo of the quad-sum
        // at fl[(b*16 + (q^b))*4 + jo]  (q^b swizzle -> 2-way banks, free).
        // acc is read with STATIC indices only (rule #20): the jo-component
        // pick is a cndmask chain over the four static quad-sums.
#pragma unroll
        for (int b = 0; b < 16; ++b) {
            const float qs0 = quad_sum(acc[b][0]);
            const float qs1 = quad_sum(acc[b][1]);
            const float qs2 = quad_sum(acc[b][2]);
            const float qs3 = quad_sum(acc[b][3]);
            const float v = (jo == 0) ? qs0 : (jo == 1) ? qs1
                          : (jo == 2) ? qs2 : qs3;
            fr[(b << 6) + ((q ^ b) << 2) + jo] = v;
            acc[b][0] = 0.f; acc[b][1] = 0.f; acc[b][2] = 0.f; acc[b][3] = 0.f;
        }
        // Read: lane (bsel=q, jo) sums its output's 16 quad-sums.
        {
            float s = 0.f;
#pragma unroll
            for (int k = 0; k < 16; ++k)
                s += fr[(q << 6) + ((k ^ q) << 2) + jo];
            wsb[(q << 7) + u * 16 + wv * 4 + jo] = s;   // private slab store
        }
    }
}

// Reduce: out[bo] += sum_s ws[s][bo].  Grid 64 = 8 bo-chunks x 8 s-chunks;
// threads adjacent in bo -> every load coalesced. Atomic fan-in 8 (trivial).
__global__ __launch_bounds__(256, 4)
void reduce_ws_kernel(const float* __restrict__ ws, float* __restrict__ out) {
    const int bo = ((blockIdx.x & 7) << 8) + threadIdx.x;
    const int s0 = (blockIdx.x >> 3) << 7;
    const float* p = ws + (size_t)s0 * 2048 + bo;
    float s = 0.f;
#pragma unroll 8
    for (int i = 0; i < 128; ++i) s += p[(size_t)i * 2048];
    atomicAdd(out + bo, s);
}

extern "C" void kernel_launch(void* const* d_in, const int* in_sizes, int n_in,
                              void* d_out, int out_size, void* d_ws, size_t ws_size,
                              hipStream_t stream) {
    const float* x    = (const float*)d_in[0];   // [16,128,4096]
    const float* wgt  = (const float*)d_in[1];   // [128,128,4096]
    const float* bias = (const float*)d_in[2];   // [128]
    float* out = (float*)d_out;                  // [16,128,1]
    float* ws  = (float*)d_ws;                   // >= 8 MB workspace
    (void)in_sizes; (void)n_in; (void)ws_size; (void)out_size;

    init_out_kernel<<<8, 256, 0, stream>>>(bias, out);
    conv_partial_kernel<<<1024, 256, 0, stream>>>(x, wgt, ws);
    reduce_ws_kernel<<<64, 256, 0, stream>>>(ws, out);
}